// Round 1
// baseline (1211.916 us; speedup 1.0000x reference)
//
#include <hip/hip_runtime.h>

// ---------------------------------------------------------------------------
// LSTM_Encoder: emb-concat -> 2-layer BiLSTM (H=200/dir) -> span pack
// B=16, L=128, IN=1218, H=200, 4H=800, LSTM_DIM=400, SMAX=8001
// ---------------------------------------------------------------------------

typedef short s16x8 __attribute__((ext_vector_type(8)));
typedef float f32x4 __attribute__((ext_vector_type(4)));

#define MFMA16(a, b, c) __builtin_amdgcn_mfma_f32_16x16x32_bf16(a, b, c, 0, 0, 0)

__device__ __forceinline__ unsigned short f2b(float f) {
    union { float f; unsigned u; } v; v.f = f;
    unsigned r = v.u + 0x7FFFu + ((v.u >> 16) & 1u);   // RNE
    return (unsigned short)(r >> 16);
}

// ---------------- embedding concat -> bf16 [2048][1248] ---------------------
__global__ __launch_bounds__(256) void k_embed(
    const float* __restrict__ ext, const float* __restrict__ wrd,
    const float* __restrict__ pos, const float* __restrict__ dep,
    const float* __restrict__ ent, const float* __restrict__ iob,
    const float* __restrict__ bert,
    const int* __restrict__ wi, const int* __restrict__ pi,
    const int* __restrict__ di, const int* __restrict__ ei,
    const int* __restrict__ ii, unsigned short* __restrict__ emb)
{
    int r = blockIdx.x;                 // b*128 + l
    int w  = wi[r];
    int wid = (w >= 20000) ? 1 : w;
    int p = pi[r], dd = di[r], e = ei[r], io = ii[r];
    for (int c = threadIdx.x; c < 1248; c += 256) {
        float v;
        if      (c < 300)  v = ext[(size_t)w * 300 + c] + wrd[(size_t)wid * 300 + c];
        else if (c < 350)  v = pos[p * 50 + (c - 300)];
        else if (c < 400)  v = dep[dd * 50 + (c - 350)];
        else if (c < 425)  v = ent[e * 25 + (c - 400)];
        else if (c < 450)  v = iob[io * 25 + (c - 425)];
        else if (c < 1218) v = bert[(size_t)r * 768 + (c - 450)];
        else               v = 0.f;
        emb[(size_t)r * 1248 + c] = f2b(v);
    }
}

// ---------------- weight converts ------------------------------------------
__global__ __launch_bounds__(256) void k_cvt_wih(
    const float* __restrict__ src, unsigned short* __restrict__ dst, int K, int Kp)
{
    int n = blockIdx.x;                 // 0..1599
    for (int c = threadIdx.x; c < Kp; c += 256)
        dst[(size_t)n * Kp + c] = f2b(c < K ? src[(size_t)n * K + c] : 0.f);
}

// whh (2,800,200) fp32 -> packed MFMA-B frags: [d][tile(50)][kf(7)][lane(64)][8]
__global__ __launch_bounds__(64) void k_cvt_whh(
    const float* __restrict__ src, unsigned short* __restrict__ dst)
{
    int blk = blockIdx.x;               // d*350 + t*7 + kf   (700 blocks)
    int kf = blk % 7, t = (blk / 7) % 50, d = blk / 350;
    int lane = threadIdx.x;
    int n = t * 16 + (lane & 15);
    int k0 = kf * 32 + (lane >> 4) * 8;
    for (int j = 0; j < 8; ++j) {
        int k = k0 + j;
        float v = (k < 200) ? src[((size_t)d * 800 + n) * 200 + k] : 0.f;
        dst[(size_t)blk * 512 + lane * 8 + j] = f2b(v);
    }
}

__global__ __launch_bounds__(256) void k_bias(
    const float* __restrict__ bih, const float* __restrict__ bhh, float* __restrict__ out)
{
    int i = blockIdx.x * 256 + threadIdx.x;
    if (i < 1600) out[i] = bih[i] + bhh[i];
}

__global__ __launch_bounds__(64) void k_lens(
    const int* __restrict__ wi, int* __restrict__ lens, float* __restrict__ outTail)
{
    int b = threadIdx.x;
    if (b < 16) {
        int c = 0;
        for (int l = 0; l < 128; ++l) c += (wi[b * 128 + l] != 0);
        lens[b] = c;
        outTail[b] = (float)(c - 2);
    }
}

// ---------------- input-projection GEMM ------------------------------------
// gx[(d*128+l)*16+b][800] = emb[b*128+l][:] . Wih[d*800+g][:] + bias
// per-wave 16x64 strip, direct-fragment loads, K-loop of 32.
__global__ __launch_bounds__(256) void k_gemm(
    const unsigned short* __restrict__ A, const unsigned short* __restrict__ W,
    const float* __restrict__ bias, float* __restrict__ gx, int lda, int nkf)
{
    int wave = (blockIdx.x << 2) | (threadIdx.x >> 6);  // 0..3199
    int lane = threadIdx.x & 63;
    int sm = (wave / 25) * 16;
    int sn = (wave % 25) * 64;
    int l15 = lane & 15, q = lane >> 4;

    const unsigned short* ap = A + (size_t)(sm + l15) * lda + q * 8;
    const unsigned short* wp = W + (size_t)(sn + l15) * lda + q * 8;

    f32x4 acc[4];
    #pragma unroll
    for (int t = 0; t < 4; ++t) acc[t] = 0.f;

    for (int kf = 0; kf < nkf; ++kf) {
        s16x8 a = *(const s16x8*)(ap + kf * 32);
        #pragma unroll
        for (int t = 0; t < 4; ++t) {
            s16x8 b = *(const s16x8*)(wp + (size_t)(t * 16) * lda + kf * 32);
            acc[t] = MFMA16(a, b, acc[t]);
        }
    }
    int m0 = sm + q * 4;
    int bb = m0 >> 7;
    #pragma unroll
    for (int t = 0; t < 4; ++t) {
        int n = sn + t * 16 + l15;
        int d = (n >= 800) ? 1 : 0;
        int rem = n - d * 800;
        float bs = bias[n];
        #pragma unroll
        for (int r = 0; r < 4; ++r) {
            int l = (m0 + r) & 127;
            gx[(size_t)((d * 128 + l) * 16 + bb) * 800 + rem] = acc[t][r] + bs;
        }
    }
}

// ---------------- recurrence: one WG per direction -------------------------
// 512 threads (8 waves). Whh: 5 tiles/wave in VGPRs + tiles 40..49 in LDS.
// LDS: Bl 71680 B | h-frag 7168 B | g 16x802 f32 51328 B  = 130176 B
__global__ __launch_bounds__(512) void k_rec(
    const float* __restrict__ gx,            // [2][128][16][800]
    const unsigned short* __restrict__ whhp, // packed [2][50][7][64][8]
    const int* __restrict__ wi,              // [16][128]
    unsigned short* __restrict__ outb, int ldb,  // bf16 [2048][ldb] or null
    float* __restrict__ hf, float* __restrict__ hb) // [16][128][200] or null
{
    extern __shared__ char smem[];
    unsigned short* Bl  = (unsigned short*)smem;            // 35840 bf16
    unsigned short* hfr = (unsigned short*)(smem + 71680);  // 3584 bf16
    float*          g   = (float*)(smem + 78848);           // 12832 f32

    const int d   = blockIdx.x;
    const int tid = threadIdx.x;
    const int w = tid >> 6, lane = tid & 63;
    const int l15 = lane & 15, q = lane >> 4;

    // stage LDS B tiles 40..49
    {
        const float4* src = (const float4*)(whhp + (size_t)d * 179200 + 143360);
        float4* dst = (float4*)Bl;
        for (int i = tid; i < 4480; i += 512) dst[i] = src[i];
    }
    // zero h frags (incl. k-pad 200..223)
    for (int i = tid; i < 1792; i += 512) ((float*)hfr)[i] = 0.f;

    // resident B tiles: wave w owns tiles w+8i, i=0..4
    s16x8 Bv[5][7];
    #pragma unroll
    for (int i = 0; i < 5; ++i)
        #pragma unroll
        for (int kf = 0; kf < 7; ++kf)
            Bv[i][kf] = *(const s16x8*)(whhp + (size_t)d * 179200 +
                                        (size_t)((w + 8 * i) * 7 + kf) * 512 + lane * 8);

    float c0[4] = {0.f, 0.f, 0.f, 0.f};
    float c1[4] = {0.f, 0.f, 0.f, 0.f};
    const int gb = tid >> 6;   // gate-phase batch base (0..7)
    const int gj = tid & 63;

    __syncthreads();

    for (int t = 0; t < 128; ++t) {
        const int l = d ? (127 - t) : t;
        const float* gxl = gx + (size_t)(d * 128 + l) * 12800;

        // prefetch gate inputs (consumed after the matmul barrier)
        float gp[2][4][4];
        #pragma unroll
        for (int bh = 0; bh < 2; ++bh) {
            int b_ = gb + 8 * bh;
            #pragma unroll
            for (int gg = 0; gg < 4; ++gg)
                #pragma unroll
                for (int ji = 0; ji < 4; ++ji) {
                    int j = gj + 64 * ji;
                    gp[bh][gg][ji] = (j < 200) ? gxl[b_ * 800 + gg * 200 + j] : 0.f;
                }
        }

        // phase 1: g_hw = h @ Whh^T
        f32x4 acc[7];
        #pragma unroll
        for (int i = 0; i < 7; ++i) acc[i] = 0.f;
        #pragma unroll
        for (int kf = 0; kf < 7; ++kf) {
            s16x8 a = *(const s16x8*)(hfr + kf * 512 + lane * 8);
            #pragma unroll
            for (int i = 0; i < 5; ++i) acc[i] = MFMA16(a, Bv[i][kf], acc[i]);
            s16x8 b5 = *(const s16x8*)(Bl + (size_t)(w * 7 + kf) * 512 + lane * 8);
            acc[5] = MFMA16(a, b5, acc[5]);
            if (w < 2) {
                s16x8 b6 = *(const s16x8*)(Bl + (size_t)((8 + w) * 7 + kf) * 512 + lane * 8);
                acc[6] = MFMA16(a, b6, acc[6]);
            }
        }
        // write g (C-frag: col=l15, row=q*4+r)
        #pragma unroll
        for (int i = 0; i < 5; ++i) {
            int n = (w + 8 * i) * 16 + l15;
            #pragma unroll
            for (int r = 0; r < 4; ++r) g[(q * 4 + r) * 802 + n] = acc[i][r];
        }
        {
            int n = (40 + w) * 16 + l15;
            #pragma unroll
            for (int r = 0; r < 4; ++r) g[(q * 4 + r) * 802 + n] = acc[5][r];
        }
        if (w < 2) {
            int n = (48 + w) * 16 + l15;
            #pragma unroll
            for (int r = 0; r < 4; ++r) g[(q * 4 + r) * 802 + n] = acc[6][r];
        }
        __syncthreads();

        // phase 2: gates
        #pragma unroll
        for (int bh = 0; bh < 2; ++bh) {
            int b_ = gb + 8 * bh;
            bool mt = (wi[b_ * 128 + l] != 0);
            float* cc = bh ? c1 : c0;
            #pragma unroll
            for (int ji = 0; ji < 4; ++ji) {
                int j = gj + 64 * ji;
                if (j < 200) {
                    float giv = g[b_ * 802 + j]       + gp[bh][0][ji];
                    float gfv = g[b_ * 802 + 200 + j] + gp[bh][1][ji];
                    float ggv = g[b_ * 802 + 400 + j] + gp[bh][2][ji];
                    float gov = g[b_ * 802 + 600 + j] + gp[bh][3][ji];
                    // sigmoid: 1/(1+2^(-x*log2e)) — safe at extremes (inf -> rcp -> 0)
                    float si = __builtin_amdgcn_rcpf(1.f + __builtin_amdgcn_exp2f(-1.442695041f * giv));
                    float sf = __builtin_amdgcn_rcpf(1.f + __builtin_amdgcn_exp2f(-1.442695041f * gfv));
                    float so = __builtin_amdgcn_rcpf(1.f + __builtin_amdgcn_exp2f(-1.442695041f * gov));
                    // tanh via |x| form (overflow-safe)
                    float ag = fabsf(ggv);
                    float eg = __builtin_amdgcn_exp2f(-2.885390082f * ag);
                    float tg = (1.f - eg) * __builtin_amdgcn_rcpf(1.f + eg);
                    tg = copysignf(tg, ggv);
                    float cn = sf * cc[ji] + si * tg;
                    float ac = fabsf(cn);
                    float ec = __builtin_amdgcn_exp2f(-2.885390082f * ac);
                    float tc = (1.f - ec) * __builtin_amdgcn_rcpf(1.f + ec);
                    tc = copysignf(tc, cn);
                    float hn = so * tc;
                    float outv;
                    if (mt) {
                        cc[ji] = cn;
                        int kf = j >> 5, qq = (j >> 3) & 3, jj = j & 7;
                        hfr[kf * 512 + (qq * 16 + b_) * 8 + jj] = f2b(hn);
                        outv = hn;
                    } else {
                        outv = 0.f;
                    }
                    int row = b_ * 128 + l;
                    if (outb) outb[(size_t)row * ldb + d * 200 + j] = f2b(outv);
                    float* fo = d ? hb : hf;
                    if (fo) fo[(size_t)row * 200 + j] = outv;
                }
            }
        }
        __syncthreads();
    }
}

// ---------------- span pack ------------------------------------------------
// block = one (b, s) row of 400 floats; 128 threads, t<100 write float4.
__global__ __launch_bounds__(128) void k_span(
    const float* __restrict__ hf, const float* __restrict__ hb,
    const int* __restrict__ lens, float* __restrict__ out)
{
    int blk = blockIdx.x;
    int b = blk / 8001, s = blk % 8001;
    int t = threadIdx.x;
    if (t >= 100) return;
    float4* orow = (float4*)(out + (size_t)blk * 400);
    int len = lens[b];
    int M = len - 2;
    int np = M * (M + 1) / 2;
    if (s >= np) {
        float4 z; z.x = z.y = z.z = z.w = 0.f;
        orow[t] = z;
        return;
    }
    // find i: prefix(i) = i*M - i(i-1)/2 <= s, then fix up
    float disc = (float)((2 * M + 1) * (2 * M + 1) - 8 * s);
    int i = (int)(((float)(2 * M + 1) - sqrtf(disc)) * 0.5f);
    if (i < 0) i = 0;
    if (i > M - 1) i = M - 1;
    #define PREF(x) ((x) * M - (x) * ((x) - 1) / 2)
    while (i > 0 && PREF(i) > s) --i;
    while (PREF(i + 1) <= s) ++i;
    int j = i + 1 + (s - PREF(i));
    #undef PREF

    if (t < 50) {
        const float4* pj = (const float4*)(hf + (size_t)(b * 128 + j) * 200);
        const float4* pi = (const float4*)(hf + (size_t)(b * 128 + i) * 200);
        float4 aa = pj[t], bb = pi[t], rr;
        rr.x = aa.x - bb.x; rr.y = aa.y - bb.y; rr.z = aa.z - bb.z; rr.w = aa.w - bb.w;
        orow[t] = rr;
    } else {
        int t2 = t - 50;
        const float4* pi = (const float4*)(hb + (size_t)(b * 128 + i + 1) * 200);
        const float4* pj = (const float4*)(hb + (size_t)(b * 128 + j + 1) * 200);
        float4 aa = pi[t2], bb = pj[t2], rr;
        rr.x = aa.x - bb.x; rr.y = aa.y - bb.y; rr.z = aa.z - bb.z; rr.w = aa.w - bb.w;
        orow[t] = rr;
    }
}

// ---------------------------------------------------------------------------
extern "C" void kernel_launch(void* const* d_in, const int* in_sizes, int n_in,
                              void* d_out, int out_size, void* d_ws, size_t ws_size,
                              hipStream_t stream)
{
    const float* ext  = (const float*)d_in[0];
    const float* wrd  = (const float*)d_in[1];
    const float* pos  = (const float*)d_in[2];
    const float* dep  = (const float*)d_in[3];
    const float* ent  = (const float*)d_in[4];
    const float* iob  = (const float*)d_in[5];
    const float* wih0 = (const float*)d_in[6];
    const float* whh0 = (const float*)d_in[7];
    const float* bih0 = (const float*)d_in[8];
    const float* bhh0 = (const float*)d_in[9];
    const float* wih1 = (const float*)d_in[10];
    const float* whh1 = (const float*)d_in[11];
    const float* bih1 = (const float*)d_in[12];
    const float* bhh1 = (const float*)d_in[13];
    const float* bert = (const float*)d_in[14];
    const int* wi = (const int*)d_in[15];
    const int* pi = (const int*)d_in[16];
    const int* di = (const int*)d_in[17];
    const int* ei = (const int*)d_in[18];
    const int* ii = (const int*)d_in[19];
    float* out = (float*)d_out;

    char* ws = (char*)d_ws;
    unsigned short* emb   = (unsigned short*)(ws + 0);         // 5,111,808
    unsigned short* wih0b = (unsigned short*)(ws + 5111808);   // 3,993,600
    unsigned short* wih1b = (unsigned short*)(ws + 9105408);   // 1,331,200
    unsigned short* whh0p = (unsigned short*)(ws + 10436608);  // 716,800
    unsigned short* whh1p = (unsigned short*)(ws + 11153408);  // 716,800
    float*          bias0 = (float*)(ws + 11870208);           // 6,400
    float*          bias1 = (float*)(ws + 11876608);           // 6,400
    int*            lens  = (int*)(ws + 11883008);             // 64
    float*          gx0   = (float*)(ws + 11883072);           // 13,107,200
    float*          gx1   = (float*)(ws + 24990272);           // 13,107,200
    unsigned short* out0b = (unsigned short*)(ws + 38097472);  // 1,703,936
    float*          hfv   = (float*)(ws + 39801408);           // 1,638,400
    float*          hbv   = (float*)(ws + 41439808);           // 1,638,400  (end 43,078,208)

    hipFuncSetAttribute((const void*)k_rec,
                        hipFuncAttributeMaxDynamicSharedMemorySize, 130176);

    k_lens <<<1, 64, 0, stream>>>(wi, lens, out + 51206400);
    k_embed<<<2048, 256, 0, stream>>>(ext, wrd, pos, dep, ent, iob, bert,
                                      wi, pi, di, ei, ii, emb);
    k_cvt_wih<<<1600, 256, 0, stream>>>(wih0, wih0b, 1218, 1248);
    k_cvt_wih<<<1600, 256, 0, stream>>>(wih1, wih1b, 400, 416);
    k_cvt_whh<<<700, 64, 0, stream>>>(whh0, whh0p);
    k_cvt_whh<<<700, 64, 0, stream>>>(whh1, whh1p);
    k_bias<<<7, 256, 0, stream>>>(bih0, bhh0, bias0);
    k_bias<<<7, 256, 0, stream>>>(bih1, bhh1, bias1);
    hipMemsetAsync(out0b, 0, 1703936, stream);   // zero pad cols 400..415

    k_gemm<<<800, 256, 0, stream>>>(emb, wih0b, bias0, gx0, 1248, 39);
    k_rec <<<2, 512, 130176, stream>>>(gx0, whh0p, wi, out0b, 416, nullptr, nullptr);
    k_gemm<<<800, 256, 0, stream>>>(out0b, wih1b, bias1, gx1, 416, 13);
    k_rec <<<2, 512, 130176, stream>>>(gx1, whh1p, wi, nullptr, 0, hfv, hbv);
    k_span<<<16 * 8001, 128, 0, stream>>>(hfv, hbv, lens, out);
}